// Round 3
// baseline (102.627 us; speedup 1.0000x reference)
//
#include <hip/hip_runtime.h>

// Semantics (derived from reference's permute + raw reshape, verified by flat-index algebra):
//   out_flat[l*128 + c] = sum_{k=0..8} in[c][h-1+k/3][w-1+k%3] * W[((h&1)*256 + w)*128 + c][k]
//   l = h*256 + w; zero padding outside [0,256)^2.
//
// Block: 256 thr = 32 ch x 8 w; each thread streams 32 h-rows with a 3x3 register
// window (rotate A<-B<-C; only row h+1 is read from LDS each step: 3 ds_read_b32).
// Both weight parities (18 f32) in registers. Input staged through a 16-row LDS ring,
// T14 split: issue global loads for row h+12 at iter i, land (ds_write) at iter i+8.
// Full unroll => all ring offsets are compile-time immediates.
// Grid 1024 = 4 c-slices x 32 w-slices x 8 h-slices, XCD-chunked (each XCD's working
// set = 32ch x 128w x 256h x 4B = 4MB = one L2).

#define NCH  128
#define C_CH 32
#define W_CH 8
#define COLS 10          // w0-1 .. w0+8
#define CPAD 11          // odd -> conflict-free LDS
#define RSTR (C_CH*CPAD) // 352 floats per ring row
#define RING 16
#define NIT  32
#define DIST 12          // stage row h0+DIST+i at iter i
#define LAND 8           // land it LAND iters later
#define NSTG 21          // stage iters: rows h0+12 .. h0+32 (prologue covers h0-1..h0+11)

__global__ __launch_bounds__(256)
void conv2d_local_kernel(const float* __restrict__ in,
                         const float* __restrict__ wgt,
                         float* __restrict__ out) {
    __shared__ float li[RING * RSTR];   // 22528 B

    const int bid = blockIdx.x;
    const int swz = (bid & 7) * 128 + (bid >> 3);
    const int cs  = swz >> 8;           // 0..3
    const int ws  = (swz & 255) >> 3;   // 0..31
    const int hs  = swz & 7;            // 0..7

    const int c0 = cs * C_CH;
    const int w0 = ws * W_CH;
    const int h0 = hs * NIT;            // multiple of 32 -> h0 & 15 == 0

    const int t  = threadIdx.x;
    const int c  = t & 31;
    const int wo = t >> 5;              // 0..7

    // ---- weights: 2 parities x 9, in registers (rows are 36B-contiguous per parity)
    const float* wb = wgt + (size_t)((w0 + wo) * NCH + c0 + c) * 9;
    float wp0[9], wp1[9];
    #pragma unroll
    for (int k = 0; k < 9; ++k) {
        wp0[k] = wb[k];
        wp1[k] = wb[(size_t)256 * NCH * 9 + k];
    }

    // ---- staging geometry: row = 320 elems; e0 = t, e1 = 256+t (t<64 only)
    const int cs0 = t / 10,          col0 = t - cs0 * 10;
    const int cs1 = (256 + t) / 10,  col1 = (256 + t) - cs1 * 10;
    const bool has1 = t < 64;
    const int gw0 = w0 - 1 + col0;  const bool okw0 = (unsigned)gw0 < 256u;
    const int gw1 = w0 - 1 + col1;  const bool okw1 = (unsigned)gw1 < 256u;
    const float* in0 = in + (((size_t)(c0 + cs0)) << 16) + (okw0 ? gw0 : 0);
    const float* in1 = in + (((size_t)(c0 + cs1)) << 16) + (okw1 ? gw1 : 0);
    const int ld0 = cs0 * CPAD + col0;
    const int ld1 = cs1 * CPAD + col1;

    // ---- prologue: stage rows h0-1 .. h0+11 (13 rows)
    for (int e = t; e < 13 * C_CH * COLS; e += 256) {
        int r   = e / (C_CH * COLS);
        int re  = e - r * (C_CH * COLS);
        int cc  = re / COLS;
        int col = re - cc * COLS;
        int gh  = h0 - 1 + r;
        int gw  = w0 - 1 + col;
        float v = 0.f;
        if ((unsigned)gh < 256u && (unsigned)gw < 256u)
            v = in[(((size_t)(c0 + cc)) << 16) + (gh << 8) + gw];
        li[((gh + RING) & 15) * RSTR + cc * CPAD + col] = v;
    }
    __syncthreads();

    // ---- init window: A = row h0-1 (slot 15), B = row h0 (slot 0)
    const float* lrd = li + c * CPAD + wo;
    float A0, A1, A2, B0, B1, B2;
    { const float* p = lrd + 15 * RSTR; A0 = p[0]; A1 = p[1]; A2 = p[2]; }
    { const float* p = lrd;             B0 = p[0]; B1 = p[1]; B2 = p[2]; }

    float sv0[NIT], sv1[NIT];           // statically indexed under full unroll
    const size_t obase = (size_t)((h0 << 8) + w0 + wo) * NCH + c0 + c;

    #pragma unroll
    for (int i = 0; i < NIT; ++i) {
        // (a) issue stage loads for row h0+DIST+i
        if (i < NSTG) {
            const int gh = h0 + DIST + i;
            float v0 = 0.f, v1 = 0.f;
            if (okw0 && (unsigned)gh < 256u) v0 = in0[gh << 8];
            if (has1 && okw1 && (unsigned)gh < 256u) v1 = in1[gh << 8];
            sv0[i] = v0; sv1[i] = v1;
        }
        // (b) read next row h0+i+1 from ring slot (i+1)&15  (3 x ds_read_b32, imm offset)
        float C0, C1, C2;
        { const float* p = lrd + ((i + 1) & 15) * RSTR; C0 = p[0]; C1 = p[1]; C2 = p[2]; }
        // (c) compute h = h0+i; parity = i&1 (h0 even) -> static weight select
        const float* wp = (i & 1) ? wp1 : wp0;
        float acc = fmaf(wp[0], A0, fmaf(wp[1], A1, fmaf(wp[2], A2,
                    fmaf(wp[3], B0, fmaf(wp[4], B1, fmaf(wp[5], B2,
                    fmaf(wp[6], C0, fmaf(wp[7], C1, wp[8] * C2))))))));
        out[obase + (size_t)i * (256 * NCH)] = acc;
        // rotate window
        A0 = B0; A1 = B1; A2 = B2;
        B0 = C0; B1 = C1; B2 = C2;
        // (d) land staged row from iter i-LAND into slot (i+4)&15
        //     reads this iter touch slots (i-1..i+1)&15 -> disjoint at skew <= 1
        if (i >= LAND && i - LAND < NSTG) {
            const int j = i - LAND;
            li[((DIST + j) & 15) * RSTR + ld0] = sv0[j];
            if (has1) li[((DIST + j) & 15) * RSTR + ld1] = sv1[j];
        }
        __syncthreads();
    }
}

extern "C" void kernel_launch(void* const* d_in, const int* in_sizes, int n_in,
                              void* d_out, int out_size, void* d_ws, size_t ws_size,
                              hipStream_t stream) {
    (void)in_sizes; (void)n_in; (void)d_ws; (void)ws_size; (void)out_size;
    const float* in = (const float*)d_in[0];   // (1,128,256,256) f32
    const float* w  = (const float*)d_in[1];   // (65536,9) f32
    float* out      = (float*)d_out;           // (1,128,256,256) f32
    conv2d_local_kernel<<<dim3(1024), dim3(256), 0, stream>>>(in, w, out);
}

// Round 6
// 101.328 us; speedup vs baseline: 1.0128x; 1.0128x over previous
//
#include <hip/hip_runtime.h>

// Semantics (verified, passed round-3 correctness):
//   out_flat[l*128 + c] = sum_{k=0..8} in[c][h-1+k/3][w-1+k%3] * W[((h&1)*256 + w)*128 + c][k]
//   l = h*256 + w; zero padding outside [0,256)^2.
//
// Block 256 thr = 32 ch x 8 w; streams 16 h-rows, 2 per iteration (parity-paired so
// wp0/wp1 are literal-indexed -> never scratch). 3x4-row register window A,B,C,D.
// Input LDS ring of 8 rows; staged loads held in NAMED scalars for exactly one
// iteration (issue i, land i+1) -> scratch-proof regardless of unroll.
// Grid 2048 = 4 cs x 32 ws x 16 hs, XCD-chunked; 8 blocks/CU co-resident.

#define NCH  128
#define C_CH 32
#define COLS 10          // w0-1 .. w0+8
#define CPAD 11          // odd stride -> conflict-free LDS
#define RSTR (C_CH*CPAD) // 352 floats per ring row
#define RING 8
#define NIT  16

__global__ __launch_bounds__(256)
void conv2d_local_kernel(const float* __restrict__ in,
                         const float* __restrict__ wgt,
                         float* __restrict__ out) {
    __shared__ float li[RING * RSTR];   // 11264 B

    const int bid = blockIdx.x;
    const int swz = (bid & 7) * 256 + (bid >> 3);
    const int cs  = swz >> 9;           // 0..3
    const int ws  = (swz >> 4) & 31;    // 0..31
    const int hs  = swz & 15;           // 0..15

    const int c0 = cs * C_CH;
    const int w0 = ws * 8;
    const int h0 = hs * NIT;            // multiple of 16 -> (h0 + r) & 7 == r & 7

    const int t  = threadIdx.x;
    const int c  = t & 31;
    const int wo = t >> 5;

    // ---- weights: both parities, literal-indexed registers
    const float* wb = wgt + (size_t)((w0 + wo) * NCH + c0 + c) * 9;
    float wp0[9], wp1[9];
    #pragma unroll
    for (int k = 0; k < 9; ++k) { wp0[k] = wb[k]; wp1[k] = wb[256 * NCH * 9 + k]; }

    // ---- staging geometry: ring row = 32ch x 10col = 320 elems; e0 = t, e1 = 256+t (t<64)
    const int cs0 = t / COLS,         col0 = t - cs0 * COLS;
    const int cs1 = (256 + t) / COLS, col1 = (256 + t) - cs1 * COLS;
    const bool has1 = t < 64;
    const int gw0 = w0 - 1 + col0;  const bool okw0 = (unsigned)gw0 < 256u;
    const int gw1 = w0 - 1 + col1;  const bool okw1 = (unsigned)gw1 < 256u;
    const float* in0 = in + (((size_t)(c0 + cs0)) << 16) + (okw0 ? gw0 : 0);
    const float* in1 = in + (((size_t)(c0 + cs1)) << 16) + (okw1 ? gw1 : 0);
    const int ld0 = cs0 * CPAD + col0;
    const int ld1 = cs1 * CPAD + col1;

    // ---- prologue: stage rows h0-1 .. h0+5 into slots 7,0,1,...,5
    for (int e = t; e < 7 * C_CH * COLS; e += 256) {
        int r   = e / (C_CH * COLS);
        int re  = e - r * (C_CH * COLS);
        int cc  = re / COLS;
        int col = re - cc * COLS;
        int gh  = h0 - 1 + r;
        int gw  = w0 - 1 + col;
        float v = 0.f;
        if ((unsigned)gh < 256u && (unsigned)gw < 256u)
            v = in[(((size_t)(c0 + cc)) << 16) + (gh << 8) + gw];
        li[(gh & 7) * RSTR + cc * CPAD + col] = v;   // gh&7 == (gh-h0)&7; -1&7 == 7
    }
    __syncthreads();

    // ---- init window: A = row h0-1 (slot 7), B = row h0 (slot 0)
    const float* lrd = li + c * CPAD + wo;
    float A0, A1, A2, B0, B1, B2;
    { const float* p = lrd + 7 * RSTR; A0 = p[0]; A1 = p[1]; A2 = p[2]; }
    { const float* p = lrd;            B0 = p[0]; B1 = p[1]; B2 = p[2]; }
    __syncthreads();   // slot 7 is overwritten by land(0) below

    // ---- pre-issue rows h0+6, h0+7 (always in-image: h0 <= 240)
    float ra0, ra1, rb0, rb1;
    {
        const int g6 = (h0 + 6) << 8, g7 = (h0 + 7) << 8;
        ra0 = okw0 ? in0[g6] : 0.f;
        ra1 = (has1 && okw1) ? in1[g6] : 0.f;
        rb0 = okw0 ? in0[g7] : 0.f;
        rb1 = (has1 && okw1) ? in1[g7] : 0.f;
    }

    #pragma unroll
    for (int i = 0; i < NIT / 2; ++i) {
        const int r6 = 2 * i + 6, r7 = 2 * i + 7;   // rows currently held in ra/rb

        // (a) read window rows 2i+1 (C), 2i+2 (D) — slots disjoint from land slots mod 8
        float C0, C1, C2, D0, D1, D2;
        { const float* p = lrd + ((2 * i + 1) & 7) * RSTR; C0 = p[0]; C1 = p[1]; C2 = p[2]; }
        { const float* p = lrd + ((2 * i + 2) & 7) * RSTR; D0 = p[0]; D1 = p[1]; D2 = p[2]; }

        // (b) land rows r6, r7 (issued one iter ago) into slots (r6&7), (r7&7)
        li[(r6 & 7) * RSTR + ld0] = ra0;
        li[(r7 & 7) * RSTR + ld0] = rb0;
        if (has1) {
            li[(r6 & 7) * RSTR + ld1] = ra1;
            li[(r7 & 7) * RSTR + ld1] = rb1;
        }

        // (c) issue rows r6+2, r7+2 into the same named scalars
        {
            int gh = h0 + r6 + 2;
            bool okh = gh < 256;
            ra0 = (okw0 && okh) ? in0[gh << 8] : 0.f;
            ra1 = (has1 && okw1 && okh) ? in1[gh << 8] : 0.f;
            gh = h0 + r7 + 2;
            okh = gh < 256;
            rb0 = (okw0 && okh) ? in0[gh << 8] : 0.f;
            rb1 = (has1 && okw1 && okh) ? in1[gh << 8] : 0.f;
        }

        // (d) compute rows h0+2i (parity 0: A,B,C) and h0+2i+1 (parity 1: B,C,D)
        float acc0 = fmaf(wp0[0], A0, fmaf(wp0[1], A1, fmaf(wp0[2], A2,
                     fmaf(wp0[3], B0, fmaf(wp0[4], B1, fmaf(wp0[5], B2,
                     fmaf(wp0[6], C0, fmaf(wp0[7], C1, wp0[8] * C2))))))));
        float acc1 = fmaf(wp1[0], B0, fmaf(wp1[1], B1, fmaf(wp1[2], B2,
                     fmaf(wp1[3], C0, fmaf(wp1[4], C1, fmaf(wp1[5], C2,
                     fmaf(wp1[6], D0, fmaf(wp1[7], D1, wp1[8] * D2))))))));
        const int h = h0 + 2 * i;
        out[(size_t)(((h)     << 8) + w0 + wo) * NCH + c0 + c] = acc0;
        out[(size_t)(((h + 1) << 8) + w0 + wo) * NCH + c0 + c] = acc1;

        // rotate window: next A = row 2i+1 (C), next B = row 2i+2 (D)
        A0 = C0; A1 = C1; A2 = C2;
        B0 = D0; B1 = D1; B2 = D2;
        __syncthreads();
    }
}

extern "C" void kernel_launch(void* const* d_in, const int* in_sizes, int n_in,
                              void* d_out, int out_size, void* d_ws, size_t ws_size,
                              hipStream_t stream) {
    (void)in_sizes; (void)n_in; (void)d_ws; (void)ws_size; (void)out_size;
    const float* in = (const float*)d_in[0];   // (1,128,256,256) f32
    const float* w  = (const float*)d_in[1];   // (65536,9) f32
    float* out      = (float*)d_out;           // (1,128,256,256) f32
    conv2d_local_kernel<<<dim3(2048), dim3(256), 0, stream>>>(in, w, out);
}